// Round 5
// baseline (255.869 us; speedup 1.0000x reference)
//
#include <hip/hip_runtime.h>
#include <math.h>

// B=16, C_in=32, C_out=32, H=256, W=256, K=16.
// S[b,i,v]   = (1/256) sum_w e^{-2pi i v w/256} * sum_h g[h] x[b,i,h,w],  g[h]=sum_{u<16} e^{-2pi i u h/256}
// blk[b,o,u,v] = sum_i S[b,i,u] * (Wr+iWi)[i,o,u,v]
// G[y,v]     = sum_u blk[u,v] e^{+2pi i u y/256}
// out[b,o,y,x] = sum_v Cc[y][v] cos(2pi v x/256) + Cs[y][v] sin(2pi v x/256)
//   with Cc[y][v] = scale_v * Re G[y,v], Cs[y][v] = -scale_v * Im G[y,v] (v>0), Cs[y][0]=0
//   -> out[64x256] = A[64x32] . T[32x256], A=[Cc|Cs], T=[cos;sin] -> MFMA bf16 (3-term split)

#define TWO_PI_OVER_256 0.02454369260617026 /* 2*pi/256 */

typedef __attribute__((ext_vector_type(8))) short short8;
typedef __attribute__((ext_vector_type(4))) float f32x4;

static __device__ inline void bf16split(unsigned short* h, unsigned short* l, float a)
{
    const unsigned u = __builtin_bit_cast(unsigned, a);
    const unsigned short hs = (unsigned short)(u >> 16);
    *h = hs;
    const float fh = __builtin_bit_cast(float, (unsigned)hs << 16);
    const float lo = a - fh;
    *l = (unsigned short)(__builtin_bit_cast(unsigned, lo) >> 16);
}

// ---------------- K0: twiddle table + swizzled DFT matrix (double precision) ----------------
// block 0: tbl[512] = cos|sin.
// blocks 1..16: Tswz for col-tile ct=blk-1. B-frag order for mfma_f32_16x16x32_bf16:
//   lane l, elem j -> k=(l>>4)*8+j, x=16*ct+(l&15). term 0 = hi bf16, term 1 = lo bf16.
//   Tswz[((term*16+ct)*64+lane)*8+j].  T[k][x] = k<16 ? cos(2pi k x/256) : sin(2pi (k-16) x/256).
__global__ __launch_bounds__(256) void k0_tables(float* __restrict__ tbl,
                                                 unsigned short* __restrict__ tswz)
{
    const int t = threadIdx.x;
    const int blk = blockIdx.x;
    if (blk == 0) {
        const double a = TWO_PI_OVER_256 * (double)t;
        tbl[t]       = (float)cos(a);
        tbl[256 + t] = (float)sin(a);
        return;
    }
    const int ct = blk - 1;
    for (int e = t; e < 1024; e += 256) {
        const int term = e >> 9;
        const int lane = (e >> 3) & 63;
        const int j = e & 7;
        const int k = ((lane >> 4) << 3) + j;
        const int x = (ct << 4) + (lane & 15);
        const int v = (k < 16) ? k : (k - 16);
        const double ang = TWO_PI_OVER_256 * (double)((v * x) & 255);
        const float val = (float)((k < 16) ? cos(ang) : sin(ang));
        const unsigned ubits = __builtin_bit_cast(unsigned, val);
        const unsigned short hi = (unsigned short)(ubits >> 16);
        unsigned short wbits;
        if (term == 0) {
            wbits = hi;
        } else {
            const float fhi = __builtin_bit_cast(float, (unsigned)hi << 16);
            const float lo = val - fhi;
            wbits = (unsigned short)(__builtin_bit_cast(unsigned, lo) >> 16);
        }
        tswz[((term * 16 + ct) * 64 + lane) * 8 + j] = wbits;
    }
}

// ---------------- K1: partial S over 64-row chunks ----------------
// grid = 512 (b*32+i) x 4 chunks = 2048 blocks.
// s_part layout: [bi][chunk][32] floats: [0..15]=Re S_partial, [16..31]=Im.
__global__ __launch_bounds__(256) void k1_partial(
    const float* __restrict__ x, const float* __restrict__ tbl,
    float* __restrict__ s_part)
{
    __shared__ float twc[256], tws[256];
    __shared__ float gre[64], gim[64];
    __shared__ float Pre[4][256], Pim[4][256];
    __shared__ float red_re[16][16], red_im[16][16];

    const int t = threadIdx.x;
    const int blk = blockIdx.x;
    const int bi = blk >> 2, chunk = blk & 3;
    const int y0 = chunk << 6;

    twc[t] = tbl[t];
    tws[t] = tbl[256 + t];
    __syncthreads();
    if (t < 64) {
        const int h = y0 + t;
        float gr = 0.f, gi = 0.f;
        #pragma unroll
        for (int u = 0; u < 16; ++u) {
            const int idx = (u * h) & 255;
            gr += twc[idx];
            gi -= tws[idx];
        }
        gre[t] = gr; gim[t] = gi;
    }
    __syncthreads();

    // Phase 1: partial P[w] = sum over 64 rows of g[h]*x[h,w]
    const float* img = x + (size_t)bi * 65536 + (size_t)y0 * 256;
    const int cg = t & 63, rg = t >> 6;
    float4 pr = {0.f,0.f,0.f,0.f}, pi = {0.f,0.f,0.f,0.f};
    #pragma unroll 4
    for (int k = 0; k < 16; ++k) {
        const int hl = rg + (k << 2);
        const float4 xv = *(const float4*)(img + (hl << 8) + (cg << 2));
        const float gr = gre[hl], gi = gim[hl];
        pr.x += gr * xv.x; pr.y += gr * xv.y; pr.z += gr * xv.z; pr.w += gr * xv.w;
        pi.x += gi * xv.x; pi.y += gi * xv.y; pi.z += gi * xv.z; pi.w += gi * xv.w;
    }
    *(float4*)&Pre[rg][cg << 2] = pr;
    *(float4*)&Pim[rg][cg << 2] = pi;
    __syncthreads();

    // Pre-reduce: fold the 4 row-group partials into Pre[0]/Pim[0].
    {
        const float sr = Pre[0][t] + Pre[1][t] + Pre[2][t] + Pre[3][t];
        const float si = Pim[0][t] + Pim[1][t] + Pim[2][t] + Pim[3][t];
        Pre[0][t] = sr;
        Pim[0][t] = si;
    }
    __syncthreads();

    // Phase 2: S_partial[v] = (1/256) sum_w P[w] e^{-2pi i v w/256}
    // w = j + 16m; twiddle advanced by rotation e^{-2pi i 16v/256} per step.
    {
        const int v = t >> 4, j = t & 15;
        const int i0 = (v * j) & 255;
        float c = twc[i0], s = tws[i0];
        const int id = (v << 4) & 255;
        const float cd = twc[id], sd = tws[id];
        float ar = 0.f, ai = 0.f;
        #pragma unroll
        for (int m = 0; m < 16; ++m) {
            const int w = j + (m << 4);
            const float prr = Pre[0][w];
            const float pii = Pim[0][w];
            ar += prr * c + pii * s;
            ai += pii * c - prr * s;
            const float nc = c * cd - s * sd;
            const float ns = s * cd + c * sd;
            c = nc; s = ns;
        }
        red_re[v][j] = ar; red_im[v][j] = ai;
    }
    __syncthreads();
    if (t < 16) {
        const float4* rr4 = (const float4*)&red_re[t][0];
        const float4* ri4 = (const float4*)&red_im[t][0];
        float ar = 0.f, ai = 0.f;
        #pragma unroll
        for (int q = 0; q < 4; ++q) {
            const float4 a = rr4[q], b = ri4[q];
            ar += a.x + a.y + a.z + a.w;
            ai += b.x + b.y + b.z + b.w;
        }
        float* sp = s_part + (size_t)bi * 128 + chunk * 32;
        sp[t]      = ar * (1.0f / 256.0f);
        sp[t + 16] = ai * (1.0f / 256.0f);
    }
}

// ---------------- K23: blk + G-coefs + MFMA synthesis, fused ----------------
// grid = 512 (b*32+o) x 4 row-chunks = 2048 blocks, 64 rows each.
// G-coef phase writes A = [Cc|Cs] as split bf16 (Ah/Al, stride 40 bf16 = 80 B rows,
// 2-way banks = free). Synthesis: out = Ah.Th + Ah.Tl + Al.Th via
// mfma_f32_16x16x32_bf16; 4 waves x 4 col-tiles x 4 row-tiles; B-frags direct
// from pre-swizzled global (L2 broadcast); D frags stored nontemporal.
__global__ __launch_bounds__(256) void k23_synth(
    const float* __restrict__ wr, const float* __restrict__ wi,
    const float* __restrict__ s_part, const float* __restrict__ tbl,
    const unsigned short* __restrict__ tswz,
    float* __restrict__ out)
{
    __shared__ float twc[256], tws[256];
    __shared__ float Sre[32][16], Sim[32][16];
    __shared__ float Btr[16 * 20], Bti[16 * 20];
    __shared__ __align__(16) unsigned short Ah[64 * 40], Al[64 * 40];

    const int t = threadIdx.x;
    const int blk = blockIdx.x;
    const int bo = blk >> 2;
    const int y0 = (blk & 3) << 6;
    const int b = bo >> 5, o = bo & 31;

    twc[t] = tbl[t];
    tws[t] = tbl[256 + t];
    // Load + sum the 4 S partials. 512 (i,u) pairs / 256 threads = 2 each.
    {
        const float* sb = s_part + (size_t)b * 4096;
        #pragma unroll
        for (int e = t; e < 512; e += 256) {
            const int i = e >> 4, u = e & 15;
            const float* p = sb + i * 128 + u;
            Sre[i][u] = p[0] + p[32] + p[64] + p[96];
            Sim[i][u] = p[16] + p[48] + p[80] + p[112];
        }
    }
    __syncthreads();

    // blk[u,v] = sum_i S[b,i,u] * W[i,o,u,v] (complex); t == u*16+v
    {
        const int u = t >> 4, v = t & 15;
        float br = 0.f, bim = 0.f;
        const float* wrp = wr + o * 256 + t;   // [i][o][u][v]
        const float* wip = wi + o * 256 + t;
        #pragma unroll 8
        for (int i = 0; i < 32; ++i) {
            const float a_re = Sre[i][u], a_im = Sim[i][u];
            const float w_re = wrp[i * 8192], w_im = wip[i * 8192];
            br  += a_re * w_re - a_im * w_im;
            bim += a_re * w_im + a_im * w_re;
        }
        Btr[v * 20 + u] = br;
        Bti[v * 20 + u] = bim;
    }
    __syncthreads();

    // G rows: thread (v = t&15, slot = t>>4) handles rows slot*4+m -> Ah/Al (split bf16).
    {
        const int v = t & 15, slot = t >> 4;
        float br[16], bim[16];
        const float4* bpr = (const float4*)&Btr[v * 20];
        const float4* bpi = (const float4*)&Bti[v * 20];
        #pragma unroll
        for (int q = 0; q < 4; ++q) {
            const float4 r4 = bpr[q], i4 = bpi[q];
            br[q*4+0]  = r4.x; br[q*4+1]  = r4.y; br[q*4+2]  = r4.z; br[q*4+3]  = r4.w;
            bim[q*4+0] = i4.x; bim[q*4+1] = i4.y; bim[q*4+2] = i4.z; bim[q*4+3] = i4.w;
        }
        const float scale = (v == 0) ? (1.0f / 256.0f) : (1.0f / 128.0f);
        #pragma unroll
        for (int m = 0; m < 4; ++m) {
            const int r = slot * 4 + m;
            const int y = y0 + r;
            const float c1 = twc[y], s1 = tws[y];   // e^{+2pi i y/256}
            float gr = br[0], gi = bim[0];
            float cc = 1.f, cs = 0.f;
            #pragma unroll
            for (int u = 1; u < 16; ++u) {
                const float nc = cc * c1 - cs * s1;
                const float ns = cc * s1 + cs * c1;
                cc = nc; cs = ns;
                gr += br[u] * cc - bim[u] * cs;
                gi += br[u] * cs + bim[u] * cc;
            }
            const float a0 = gr * scale;
            const float a1 = (v == 0) ? 0.f : (-gi * scale);
            bf16split(&Ah[r * 40 + v],      &Al[r * 40 + v],      a0);
            bf16split(&Ah[r * 40 + 16 + v], &Al[r * 40 + 16 + v], a1);
        }
    }
    __syncthreads();

    // MFMA synthesis: wave wv owns col-tiles 4*wv..4*wv+3, all 4 row-tiles.
    {
        const int lane = t & 63, wv = t >> 6;
        short8 afh[4], afl[4];
        #pragma unroll
        for (int m = 0; m < 4; ++m) {
            const int off = (m * 16 + (lane & 15)) * 40 + ((lane >> 4) << 3); // bf16 units
            afh[m] = *(const short8*)&Ah[off];
            afl[m] = *(const short8*)&Al[off];
        }
        float* outb = out + (size_t)bo * 65536 + (size_t)y0 * 256;
        #pragma unroll
        for (int q = 0; q < 4; ++q) {
            const int ct = (wv << 2) + q;
            const short8 bh = *(const short8*)&tswz[(size_t)(ct * 64 + lane) * 8];
            const short8 bl = *(const short8*)&tswz[(size_t)((16 + ct) * 64 + lane) * 8];
            #pragma unroll
            for (int m = 0; m < 4; ++m) {
                f32x4 acc = {0.f, 0.f, 0.f, 0.f};
                acc = __builtin_amdgcn_mfma_f32_16x16x32_bf16(afh[m], bh, acc, 0, 0, 0);
                acc = __builtin_amdgcn_mfma_f32_16x16x32_bf16(afh[m], bl, acc, 0, 0, 0);
                acc = __builtin_amdgcn_mfma_f32_16x16x32_bf16(afl[m], bh, acc, 0, 0, 0);
                // D frag: col = lane&15, row = (lane>>4)*4 + reg   [m89-verified]
                float* op = outb + (size_t)(16 * m + ((lane >> 4) << 2)) * 256
                                 + (ct << 4) + (lane & 15);
                #pragma unroll
                for (int reg = 0; reg < 4; ++reg)
                    __builtin_nontemporal_store(acc[reg], op + reg * 256);
            }
        }
    }
}

extern "C" void kernel_launch(void* const* d_in, const int* in_sizes, int n_in,
                              void* d_out, int out_size, void* d_ws, size_t ws_size,
                              hipStream_t stream) {
    (void)in_sizes; (void)n_in; (void)out_size; (void)ws_size;
    const float* x  = (const float*)d_in[0];
    const float* wr = (const float*)d_in[1];
    const float* wi = (const float*)d_in[2];
    float* out    = (float*)d_out;
    float* s_part = (float*)d_ws;                        // 65536 floats = 256 KB
    float* tbl    = s_part + 65536;                      // 512 floats (cos | sin)
    unsigned short* tswz = (unsigned short*)(tbl + 512); // 16384 bf16 = 32 KB

    k0_tables<<<17, 256, 0, stream>>>(tbl, tswz);
    k1_partial<<<2048, 256, 0, stream>>>(x, tbl, s_part);
    k23_synth<<<2048, 256, 0, stream>>>(wr, wi, s_part, tbl, tswz, out);
}

// Round 7
// 252.404 us; speedup vs baseline: 1.0137x; 1.0137x over previous
//
#include <hip/hip_runtime.h>
#include <math.h>

// B=16, C_in=32, C_out=32, H=256, W=256, K=16.
// S[b,i,v]   = (1/256) sum_w e^{-2pi i v w/256} * sum_h g[h] x[b,i,h,w],  g[h]=sum_{u<16} e^{-2pi i u h/256}
// blk[b,o,u,v] = sum_i S[b,i,u] * (Wr+iWi)[i,o,u,v]
// G[y,v]     = sum_u blk[u,v] e^{+2pi i u y/256}
//   -> G_re = [cos | -sin](64x32) . [br;bi](32x16),  G_im = [sin | cos] . [br;bi]   (MFMA, bf16 3-term)
// out[64x256] = A[64x32] . T[32x256], A=[Cc|Cs] (scaled G), T=[cos;sin]             (MFMA, bf16 3-term)

#define TWO_PI_OVER_256 0.02454369260617026 /* 2*pi/256 */

typedef __attribute__((ext_vector_type(8))) short short8;
typedef __attribute__((ext_vector_type(4))) float f32x4;

static __device__ inline void bf16split(unsigned short* h, unsigned short* l, float a)
{
    const unsigned u = __builtin_bit_cast(unsigned, a);
    const unsigned short hs = (unsigned short)(u >> 16);
    *h = hs;
    const float fh = __builtin_bit_cast(float, (unsigned)hs << 16);
    const float lo = a - fh;
    *l = (unsigned short)(__builtin_bit_cast(unsigned, lo) >> 16);
}

// ---------------- K0: all constant tables ----------------
// Every block: 256-angle f64 cos/sin LDS table (1 pair/thread), then derive outputs.
// block 0: tbl[512] (cos|sin) + gtab (g[h] re/im interleaved, float2[256]).
// blocks 1..16: Tswz col-tile ct=blk-1. B-frag order (HW-validated r5):
//   lane l, elem j -> k=(l>>4)*8+j, x=16*ct+(l&15); T[k][x]=k<16?cos(kx):sin((k-16)x).
//   tswz[((term*16+ct)*64+lane)*8+j], term 0=hi,1=lo bf16.
// blocks 17..48: Eswz A-frag tables for the G-MFMA. lane&15 = row-in-tile (y),
//   k=(l>>4)*8+j. p=0 (re): [cos | -sin]; p=1 (im): [sin | cos].
//   eswz[gid], gid = ((p*2+term)*16+yt)*512 + lane*8 + j.
__global__ __launch_bounds__(256) void k0_tables(
    float* __restrict__ tbl, float* __restrict__ gtab,
    unsigned short* __restrict__ tswz, unsigned short* __restrict__ eswz)
{
    __shared__ float ctb[256], stb[256];
    const int t = threadIdx.x;
    const int blk = blockIdx.x;
    {
        const double a = TWO_PI_OVER_256 * (double)t;
        ctb[t] = (float)cos(a);
        stb[t] = (float)sin(a);
    }
    __syncthreads();
    if (blk == 0) {
        tbl[t]       = ctb[t];
        tbl[256 + t] = stb[t];
        float gr = 0.f, gi = 0.f;
        #pragma unroll
        for (int u = 0; u < 16; ++u) {
            const int idx = (u * t) & 255;
            gr += ctb[idx];
            gi -= stb[idx];
        }
        gtab[2 * t]     = gr;
        gtab[2 * t + 1] = gi;
    } else if (blk <= 16) {
        const int ct = blk - 1;
        for (int e = t; e < 1024; e += 256) {
            const int term = e >> 9, lane = (e >> 3) & 63, j = e & 7;
            const int k = ((lane >> 4) << 3) + j;
            const int x = (ct << 4) + (lane & 15);
            const int v = (k < 16) ? k : (k - 16);
            const int idx = (v * x) & 255;
            const float val = (k < 16) ? ctb[idx] : stb[idx];
            unsigned short hb, lb; bf16split(&hb, &lb, val);
            tswz[((term * 16 + ct) * 64 + lane) * 8 + j] = term ? lb : hb;
        }
    } else {
        for (int e = t; e < 1024; e += 256) {
            const int gid = (blk - 17) * 1024 + e;
            const int j = gid & 7, lane = (gid >> 3) & 63;
            const int yt = (gid >> 9) & 15, pt = gid >> 13;
            const int p = pt >> 1, term = pt & 1;
            const int y = (yt << 4) + (lane & 15);
            const int k = ((lane >> 4) << 3) + j;
            const int v = (k < 16) ? k : (k - 16);
            const int idx = (v * y) & 255;
            float val;
            if (p == 0) val = (k < 16) ? ctb[idx] : -stb[idx];
            else        val = (k < 16) ? stb[idx] :  ctb[idx];
            unsigned short hb, lb; bf16split(&hb, &lb, val);
            eswz[gid] = term ? lb : hb;
        }
    }
}

// ---------------- K1: partial S over 64-row chunks ----------------
// grid = 512 (b*32+i) x 4 chunks = 2048 blocks.
// s_part layout: [bi][chunk][32] floats: [0..15]=Re S_partial, [16..31]=Im.
__global__ __launch_bounds__(256) void k1_partial(
    const float* __restrict__ x, const float* __restrict__ tbl,
    const float* __restrict__ gtab, float* __restrict__ s_part)
{
    __shared__ float twc[256], tws[256];
    __shared__ float gre[64], gim[64];
    __shared__ float Pre[4][256], Pim[4][256];
    __shared__ float red_re[16][16], red_im[16][16];

    const int t = threadIdx.x;
    const int blk = blockIdx.x;
    const int bi = blk >> 2, chunk = blk & 3;
    const int y0 = chunk << 6;

    twc[t] = tbl[t];
    tws[t] = tbl[256 + t];
    if (t < 64) {
        const float2 g = *(const float2*)(gtab + ((y0 + t) << 1));
        gre[t] = g.x; gim[t] = g.y;
    }
    __syncthreads();

    // Phase 1: partial P[w] = sum over 64 rows of g[h]*x[h,w]
    const float* img = x + (size_t)bi * 65536 + (size_t)y0 * 256;
    const int cg = t & 63, rg = t >> 6;
    float4 pr = {0.f,0.f,0.f,0.f}, pi = {0.f,0.f,0.f,0.f};
    #pragma unroll 4
    for (int k = 0; k < 16; ++k) {
        const int hl = rg + (k << 2);
        const float4 xv = *(const float4*)(img + (hl << 8) + (cg << 2));
        const float gr = gre[hl], gi = gim[hl];
        pr.x += gr * xv.x; pr.y += gr * xv.y; pr.z += gr * xv.z; pr.w += gr * xv.w;
        pi.x += gi * xv.x; pi.y += gi * xv.y; pi.z += gi * xv.z; pi.w += gi * xv.w;
    }
    *(float4*)&Pre[rg][cg << 2] = pr;
    *(float4*)&Pim[rg][cg << 2] = pi;
    __syncthreads();

    // Pre-reduce: fold the 4 row-group partials into Pre[0]/Pim[0].
    {
        const float sr = Pre[0][t] + Pre[1][t] + Pre[2][t] + Pre[3][t];
        const float si = Pim[0][t] + Pim[1][t] + Pim[2][t] + Pim[3][t];
        Pre[0][t] = sr;
        Pim[0][t] = si;
    }
    __syncthreads();

    // Phase 2: S_partial[v] = (1/256) sum_w P[w] e^{-2pi i v w/256}
    // w = j + 16m; twiddle advanced by rotation e^{-2pi i 16v/256} per step.
    {
        const int v = t >> 4, j = t & 15;
        const int i0 = (v * j) & 255;
        float c = twc[i0], s = tws[i0];
        const int id = (v << 4) & 255;
        const float cd = twc[id], sd = tws[id];
        float ar = 0.f, ai = 0.f;
        #pragma unroll
        for (int m = 0; m < 16; ++m) {
            const int w = j + (m << 4);
            const float prr = Pre[0][w];
            const float pii = Pim[0][w];
            ar += prr * c + pii * s;
            ai += pii * c - prr * s;
            const float nc = c * cd - s * sd;
            const float ns = s * cd + c * sd;
            c = nc; s = ns;
        }
        red_re[v][j] = ar; red_im[v][j] = ai;
    }
    __syncthreads();
    if (t < 16) {
        const float4* rr4 = (const float4*)&red_re[t][0];
        const float4* ri4 = (const float4*)&red_im[t][0];
        float ar = 0.f, ai = 0.f;
        #pragma unroll
        for (int q = 0; q < 4; ++q) {
            const float4 a = rr4[q], b = ri4[q];
            ar += a.x + a.y + a.z + a.w;
            ai += b.x + b.y + b.z + b.w;
        }
        float* sp = s_part + (size_t)bi * 128 + chunk * 32;
        sp[t]      = ar * (1.0f / 256.0f);
        sp[t + 16] = ai * (1.0f / 256.0f);
    }
}

// ---------------- K23: blk + MFMA G + MFMA synthesis, fused ----------------
// grid = 512 (b*32+o) x 4 row-chunks = 2048 blocks, 64 rows each.
// blk phase writes [br;bi] bf16-split directly in B-frag order (Bfh/Bfl).
// G phase: wave wv owns row-tile wv; 6 MFMAs -> Cc/Cs bf16-split into Ah/Al.
// Synthesis: out = Ah.Th + Ah.Tl + Al.Th; 4 waves x 4 col-tiles x 4 row-tiles.
__global__ __launch_bounds__(256) void k23_synth(
    const float* __restrict__ wr, const float* __restrict__ wi,
    const float* __restrict__ s_part,
    const unsigned short* __restrict__ tswz,
    const unsigned short* __restrict__ eswz,
    float* __restrict__ out)
{
    __shared__ float Sre[32][16], Sim[32][16];
    __shared__ __align__(16) unsigned short Bfh[512], Bfl[512];
    __shared__ __align__(16) unsigned short Ah[64 * 40], Al[64 * 40];

    const int t = threadIdx.x;
    const int blk = blockIdx.x;
    const int bo = blk >> 2;
    const int b = bo >> 5, o = bo & 31;

    // Load + sum the 4 S partials. 512 (i,u) pairs / 256 threads = 2 each.
    {
        const float* sb = s_part + (size_t)b * 4096;
        #pragma unroll
        for (int e = t; e < 512; e += 256) {
            const int i = e >> 4, u = e & 15;
            const float* p = sb + i * 128 + u;
            Sre[i][u] = p[0] + p[32] + p[64] + p[96];
            Sim[i][u] = p[16] + p[48] + p[80] + p[112];
        }
    }
    __syncthreads();

    // blk[u,v] = sum_i S[b,i,u] * W[i,o,u,v] (complex); t == u*16+v.
    // Write bf16-split in B-frag order: br at k=u, bi at k=16+u.
    {
        const int u = t >> 4, v = t & 15;
        float br = 0.f, bim = 0.f;
        const float* wrp = wr + o * 256 + t;   // [i][o][u][v]
        const float* wip = wi + o * 256 + t;
        #pragma unroll 8
        for (int i = 0; i < 32; ++i) {
            const float a_re = Sre[i][u], a_im = Sim[i][u];
            const float w_re = wrp[i * 8192], w_im = wip[i * 8192];
            br  += a_re * w_re - a_im * w_im;
            bim += a_re * w_im + a_im * w_re;
        }
        unsigned short h0, l0, h1, l1;
        bf16split(&h0, &l0, br);
        bf16split(&h1, &l1, bim);
        const int lr = ((((u >> 3) << 4) | v) << 3) + (u & 7);        // k=u
        const int li = ((((2 + (u >> 3)) << 4) | v) << 3) + (u & 7);  // k=16+u
        Bfh[lr] = h0; Bfl[lr] = l0;
        Bfh[li] = h1; Bfl[li] = l1;
    }
    __syncthreads();

    // G phase (MFMA): wave wv -> row-tile wv (rows 16wv..16wv+15), yt = chunk*4+wv.
    // G_re = [cos|-sin].[br;bi], G_im = [sin|cos].[br;bi]; 3-term bf16 each.
    {
        const int lane = t & 63, wv = t >> 6;
        const int yt = ((blk & 3) << 2) + wv;
        const short8 bh = *(const short8*)&Bfh[lane << 3];
        const short8 bl = *(const short8*)&Bfl[lane << 3];
        const short8 arh = *(const short8*)&eswz[(size_t)(( 0 + yt) << 9) + (lane << 3)];
        const short8 arl = *(const short8*)&eswz[(size_t)((16 + yt) << 9) + (lane << 3)];
        const short8 aih = *(const short8*)&eswz[(size_t)((32 + yt) << 9) + (lane << 3)];
        const short8 ail = *(const short8*)&eswz[(size_t)((48 + yt) << 9) + (lane << 3)];
        f32x4 gre = {0.f, 0.f, 0.f, 0.f}, gim = {0.f, 0.f, 0.f, 0.f};
        gre = __builtin_amdgcn_mfma_f32_16x16x32_bf16(arh, bh, gre, 0, 0, 0);
        gre = __builtin_amdgcn_mfma_f32_16x16x32_bf16(arh, bl, gre, 0, 0, 0);
        gre = __builtin_amdgcn_mfma_f32_16x16x32_bf16(arl, bh, gre, 0, 0, 0);
        gim = __builtin_amdgcn_mfma_f32_16x16x32_bf16(aih, bh, gim, 0, 0, 0);
        gim = __builtin_amdgcn_mfma_f32_16x16x32_bf16(aih, bl, gim, 0, 0, 0);
        gim = __builtin_amdgcn_mfma_f32_16x16x32_bf16(ail, bh, gim, 0, 0, 0);
        // D frag: v = lane&15, row = 16wv + (lane>>4)*4 + reg   [m89 / r5-validated]
        const int v = lane & 15;
        const float scale = (v == 0) ? (1.0f / 256.0f) : (1.0f / 128.0f);
        const int rbase = (wv << 4) + ((lane >> 4) << 2);
        #pragma unroll
        for (int reg = 0; reg < 4; ++reg) {
            const int r = rbase + reg;
            const float cc = gre[reg] * scale;
            const float cs = (v == 0) ? 0.f : (-gim[reg] * scale);
            bf16split(&Ah[r * 40 + v],      &Al[r * 40 + v],      cc);
            bf16split(&Ah[r * 40 + 16 + v], &Al[r * 40 + 16 + v], cs);
        }
    }
    __syncthreads();

    // MFMA synthesis: wave wv owns col-tiles 4*wv..4*wv+3, all 4 row-tiles.
    {
        const int lane = t & 63, wv = t >> 6;
        short8 afh[4], afl[4];
        #pragma unroll
        for (int m = 0; m < 4; ++m) {
            const int off = (m * 16 + (lane & 15)) * 40 + ((lane >> 4) << 3); // bf16 units
            afh[m] = *(const short8*)&Ah[off];
            afl[m] = *(const short8*)&Al[off];
        }
        float* outb = out + (size_t)bo * 65536 + (size_t)((blk & 3) << 6) * 256;
        #pragma unroll
        for (int q = 0; q < 4; ++q) {
            const int ct = (wv << 2) + q;
            const short8 bh = *(const short8*)&tswz[(size_t)(ct * 64 + lane) * 8];
            const short8 bl = *(const short8*)&tswz[(size_t)((16 + ct) * 64 + lane) * 8];
            #pragma unroll
            for (int m = 0; m < 4; ++m) {
                f32x4 acc = {0.f, 0.f, 0.f, 0.f};
                acc = __builtin_amdgcn_mfma_f32_16x16x32_bf16(afh[m], bh, acc, 0, 0, 0);
                acc = __builtin_amdgcn_mfma_f32_16x16x32_bf16(afh[m], bl, acc, 0, 0, 0);
                acc = __builtin_amdgcn_mfma_f32_16x16x32_bf16(afl[m], bh, acc, 0, 0, 0);
                float* op = outb + (size_t)(16 * m + ((lane >> 4) << 2)) * 256
                                 + (ct << 4) + (lane & 15);
                #pragma unroll
                for (int reg = 0; reg < 4; ++reg)
                    __builtin_nontemporal_store(acc[reg], op + reg * 256);
            }
        }
    }
}

extern "C" void kernel_launch(void* const* d_in, const int* in_sizes, int n_in,
                              void* d_out, int out_size, void* d_ws, size_t ws_size,
                              hipStream_t stream) {
    (void)in_sizes; (void)n_in; (void)out_size; (void)ws_size;
    const float* x  = (const float*)d_in[0];
    const float* wr = (const float*)d_in[1];
    const float* wi = (const float*)d_in[2];
    float* out    = (float*)d_out;
    float* s_part = (float*)d_ws;                         // 65536 floats = 256 KB
    float* tbl    = s_part + 65536;                       // 512 floats (cos | sin)
    float* gtab   = tbl + 512;                            // float2[256] g-table
    unsigned short* tswz = (unsigned short*)(gtab + 512); // 16384 bf16 = 32 KB
    unsigned short* eswz = tswz + 16384;                  // 32768 bf16 = 64 KB

    k0_tables<<<49, 256, 0, stream>>>(tbl, gtab, tswz, eswz);
    k1_partial<<<2048, 256, 0, stream>>>(x, tbl, gtab, s_part);
    k23_synth<<<2048, 256, 0, stream>>>(wr, wi, s_part, tswz, eswz, out);
}